// Round 1
// baseline (1390.261 us; speedup 1.0000x reference)
//
#include <hip/hip_runtime.h>
#include <hip/hip_bf16.h>

// MoE FFN, dense-masked baseline.
// T=8192 tokens, H=1024, E=8, D=2048 (expert dim), top-2 routing.
// Strategy: convert to bf16 once -> router -> per-expert {GEMM1+silu fused, GEMM2+weighted accumulate}.

#define T_TOKENS 8192
#define HID 1024
#define NEXP 8
#define ED 2048
#define ED2 4096

typedef __attribute__((ext_vector_type(8))) short bf16x8;
typedef __attribute__((ext_vector_type(4))) float f32x4;

__device__ __forceinline__ void gload_lds16(const void* g, void* lds) {
  __builtin_amdgcn_global_load_lds(
      (const __attribute__((address_space(1))) void*)g,
      (__attribute__((address_space(3))) void*)lds, 16, 0, 0);
}

// ---------------- f32 -> bf16 conversion (vectorized) ----------------
__global__ void cvt_kernel(const float* __restrict__ in, __hip_bfloat16* __restrict__ out, int n4) {
  int idx = blockIdx.x * blockDim.x + threadIdx.x;
  int stride = gridDim.x * blockDim.x;
  for (int i = idx; i < n4; i += stride) {
    float4 v = reinterpret_cast<const float4*>(in)[i];
    __hip_bfloat16 h0 = __float2bfloat16(v.x);
    __hip_bfloat16 h1 = __float2bfloat16(v.y);
    __hip_bfloat16 h2 = __float2bfloat16(v.z);
    __hip_bfloat16 h3 = __float2bfloat16(v.w);
    ushort4 o;
    o.x = *reinterpret_cast<unsigned short*>(&h0);
    o.y = *reinterpret_cast<unsigned short*>(&h1);
    o.z = *reinterpret_cast<unsigned short*>(&h2);
    o.w = *reinterpret_cast<unsigned short*>(&h3);
    reinterpret_cast<ushort4*>(out)[i] = o;
  }
}

// ---------------- router: logits -> softmax -> top2 -> renorm ----------------
__global__ __launch_bounds__(64) void router_kernel(const float* __restrict__ x,
                                                    const float* __restrict__ rw,
                                                    float* __restrict__ combine) {
  const int t = blockIdx.x;
  const int lane = threadIdx.x;
  const float* xr = x + (size_t)t * HID;
  float xv[16];
#pragma unroll
  for (int i = 0; i < 16; i++) xv[i] = xr[lane + 64 * i];
  float logit[NEXP];
#pragma unroll
  for (int e = 0; e < NEXP; e++) {
    const float* r = rw + e * HID;
    float p = 0.f;
#pragma unroll
    for (int i = 0; i < 16; i++) p += xv[i] * r[lane + 64 * i];
#pragma unroll
    for (int off = 32; off > 0; off >>= 1) p += __shfl_down(p, off);
    logit[e] = __shfl(p, 0);
  }
  if (lane == 0) {
    float mx = logit[0];
    for (int e = 1; e < NEXP; e++) mx = fmaxf(mx, logit[e]);
    float pr[NEXP];
    float se = 0.f;
    for (int e = 0; e < NEXP; e++) { pr[e] = expf(logit[e] - mx); se += pr[e]; }
    for (int e = 0; e < NEXP; e++) pr[e] /= se;
    // top-2, ties -> lowest index (matches jax.lax.top_k)
    int i0 = 0;
    for (int e = 1; e < NEXP; e++) if (pr[e] > pr[i0]) i0 = e;
    int i1 = (i0 == 0) ? 1 : 0;
    for (int e = 0; e < NEXP; e++) if (e != i0 && pr[e] > pr[i1]) i1 = e;
    float s = pr[i0] + pr[i1];
    float cw[NEXP];
    for (int e = 0; e < NEXP; e++) cw[e] = 0.f;
    cw[i0] = pr[i0] / s;
    cw[i1] = pr[i1] / s;
    for (int e = 0; e < NEXP; e++) combine[t * NEXP + e] = cw[e];
  }
}

// ---------------- GEMM1: y1 = silu(x @ Wg^T) * (x @ Wu^T), bf16 out ----------------
// A: xb [8192,1024], B: up_b for one expert [4096,1024] (rows 0..2047 gate, 2048..4095 up)
// block tile: 128 rows x 64 gate-cols (+ paired 64 up-cols). 4 waves 2x2 -> 64x32 each.
__global__ __launch_bounds__(256) void gemm1_silu(const __hip_bfloat16* __restrict__ A,
                                                  const __hip_bfloat16* __restrict__ B,
                                                  __hip_bfloat16* __restrict__ Y) {
  __shared__ __hip_bfloat16 sA[128 * 64];
  __shared__ __hip_bfloat16 sBg[64 * 64];
  __shared__ __hip_bfloat16 sBu[64 * 64];
  const int tid = threadIdx.x;
  const int w = tid >> 6, lane = tid & 63;
  const int m0 = blockIdx.x * 128;
  const int n0 = blockIdx.y * 64;
  const int wm = w >> 1, wn = w & 1;
  const int lr = lane >> 3;         // row within 8-row staging chunk
  const int lc = (lane & 7) * 8;    // col (elements) within row

  f32x4 accg[4][2] = {};
  f32x4 accu[4][2] = {};

  for (int k0 = 0; k0 < HID; k0 += 64) {
#pragma unroll
    for (int i = 0; i < 4; i++) {
      const int c = w * 4 + i;  // 0..15, 8 rows each
      gload_lds16(A + (size_t)(m0 + c * 8 + lr) * HID + k0 + lc, (char*)sA + c * 1024);
    }
#pragma unroll
    for (int i = 0; i < 2; i++) {
      const int c = w * 2 + i;  // 0..7
      gload_lds16(B + (size_t)(n0 + c * 8 + lr) * HID + k0 + lc, (char*)sBg + c * 1024);
      gload_lds16(B + (size_t)(ED + n0 + c * 8 + lr) * HID + k0 + lc, (char*)sBu + c * 1024);
    }
    __syncthreads();
#pragma unroll
    for (int ks = 0; ks < 2; ks++) {
      const int kc = ks * 32 + (lane >> 4) * 8;
      bf16x8 af[4], bg[2], bu[2];
#pragma unroll
      for (int m = 0; m < 4; m++)
        af[m] = *reinterpret_cast<const bf16x8*>(&sA[(wm * 64 + m * 16 + (lane & 15)) * 64 + kc]);
#pragma unroll
      for (int n = 0; n < 2; n++) {
        bg[n] = *reinterpret_cast<const bf16x8*>(&sBg[(wn * 32 + n * 16 + (lane & 15)) * 64 + kc]);
        bu[n] = *reinterpret_cast<const bf16x8*>(&sBu[(wn * 32 + n * 16 + (lane & 15)) * 64 + kc]);
      }
#pragma unroll
      for (int m = 0; m < 4; m++)
#pragma unroll
        for (int n = 0; n < 2; n++) {
          accg[m][n] = __builtin_amdgcn_mfma_f32_16x16x32_bf16(af[m], bg[n], accg[m][n], 0, 0, 0);
          accu[m][n] = __builtin_amdgcn_mfma_f32_16x16x32_bf16(af[m], bu[n], accu[m][n], 0, 0, 0);
        }
    }
    __syncthreads();
  }
  // epilogue: y1 = silu(g)*u  (C/D layout: col=lane&15, row=(lane>>4)*4+r)
#pragma unroll
  for (int m = 0; m < 4; m++)
#pragma unroll
    for (int n = 0; n < 2; n++) {
      const int row = m0 + wm * 64 + m * 16 + (lane >> 4) * 4;
      const int col = n0 + wn * 32 + n * 16 + (lane & 15);
#pragma unroll
      for (int r = 0; r < 4; r++) {
        float g = accg[m][n][r];
        float u = accu[m][n][r];
        float s = g / (1.f + expf(-g));
        Y[(size_t)(row + r) * ED + col] = __float2bfloat16(s * u);
      }
    }
}

// ---------------- GEMM2: out += combine[:,e] * (y1 @ down^T) ----------------
// A: y1 [8192,2048], B: down_b for expert [1024,2048]. 128x128 tile, 4 waves 2x2 -> 64x64.
__global__ __launch_bounds__(256) void gemm2_acc(const __hip_bfloat16* __restrict__ A,
                                                 const __hip_bfloat16* __restrict__ B,
                                                 const float* __restrict__ combine,
                                                 float* __restrict__ out, int e) {
  __shared__ __hip_bfloat16 sA[128 * 64];
  __shared__ __hip_bfloat16 sB[128 * 64];
  const int tid = threadIdx.x;
  const int w = tid >> 6, lane = tid & 63;
  const int m0 = blockIdx.x * 128;
  const int n0 = blockIdx.y * 128;
  const int wm = w >> 1, wn = w & 1;
  const int lr = lane >> 3;
  const int lc = (lane & 7) * 8;

  f32x4 acc[4][4] = {};

  for (int k0 = 0; k0 < ED; k0 += 64) {
#pragma unroll
    for (int i = 0; i < 4; i++) {
      const int c = w * 4 + i;
      gload_lds16(A + (size_t)(m0 + c * 8 + lr) * ED + k0 + lc, (char*)sA + c * 1024);
      gload_lds16(B + (size_t)(n0 + c * 8 + lr) * ED + k0 + lc, (char*)sB + c * 1024);
    }
    __syncthreads();
#pragma unroll
    for (int ks = 0; ks < 2; ks++) {
      const int kc = ks * 32 + (lane >> 4) * 8;
      bf16x8 af[4], bf[4];
#pragma unroll
      for (int m = 0; m < 4; m++)
        af[m] = *reinterpret_cast<const bf16x8*>(&sA[(wm * 64 + m * 16 + (lane & 15)) * 64 + kc]);
#pragma unroll
      for (int n = 0; n < 4; n++)
        bf[n] = *reinterpret_cast<const bf16x8*>(&sB[(wn * 64 + n * 16 + (lane & 15)) * 64 + kc]);
#pragma unroll
      for (int m = 0; m < 4; m++)
#pragma unroll
        for (int n = 0; n < 4; n++)
          acc[m][n] = __builtin_amdgcn_mfma_f32_16x16x32_bf16(af[m], bf[n], acc[m][n], 0, 0, 0);
    }
    __syncthreads();
  }
#pragma unroll
  for (int m = 0; m < 4; m++)
#pragma unroll
    for (int n = 0; n < 4; n++) {
      const int row = m0 + wm * 64 + m * 16 + (lane >> 4) * 4;
      const int col = n0 + wn * 64 + n * 16 + (lane & 15);
#pragma unroll
      for (int r = 0; r < 4; r++) {
        float wgt = combine[(size_t)(row + r) * NEXP + e];
        out[(size_t)(row + r) * HID + col] += wgt * acc[m][n][r];
      }
    }
}

extern "C" void kernel_launch(void* const* d_in, const int* in_sizes, int n_in,
                              void* d_out, int out_size, void* d_ws, size_t ws_size,
                              hipStream_t stream) {
  const float* x = (const float*)d_in[0];     // [4,2048,1024]
  const float* rw = (const float*)d_in[1];    // [8,1024]
  const float* up = (const float*)d_in[2];    // [8,4096,1024]
  const float* down = (const float*)d_in[3];  // [8,1024,2048]
  float* out = (float*)d_out;

  char* ws = (char*)d_ws;
  // workspace layout (bytes):
  __hip_bfloat16* xb = (__hip_bfloat16*)(ws);                     // 16,777,216
  __hip_bfloat16* upb = (__hip_bfloat16*)(ws + 16777216);         // 67,108,864
  __hip_bfloat16* downb = (__hip_bfloat16*)(ws + 83886080);       // 33,554,432
  __hip_bfloat16* y1 = (__hip_bfloat16*)(ws + 117440512);         // 33,554,432
  float* combine = (float*)(ws + 150994944);                      // 262,144 -> total ~151.3 MB

  hipMemsetAsync(d_out, 0, (size_t)out_size * sizeof(float), stream);

  cvt_kernel<<<2048, 256, 0, stream>>>(x, xb, (T_TOKENS * HID) / 4);
  cvt_kernel<<<2048, 256, 0, stream>>>(up, upb, (NEXP * ED2 * HID) / 4);
  cvt_kernel<<<2048, 256, 0, stream>>>(down, downb, (NEXP * HID * ED) / 4);
  router_kernel<<<T_TOKENS, 64, 0, stream>>>(x, rw, combine);

  dim3 g1(T_TOKENS / 128, ED / 64);    // 64 x 32
  dim3 g2(T_TOKENS / 128, HID / 128);  // 64 x 8
  for (int e = 0; e < NEXP; e++) {
    gemm1_silu<<<g1, 256, 0, stream>>>(xb, upb + (size_t)e * ED2 * HID, y1);
    gemm2_acc<<<g2, 256, 0, stream>>>(y1, downb + (size_t)e * HID * ED, combine, out, e);
  }
}

// Round 2
// 1158.684 us; speedup vs baseline: 1.1999x; 1.1999x over previous
//
#include <hip/hip_runtime.h>
#include <hip/hip_bf16.h>

// MoE FFN, sparse dispatch (top-2 of 8).
// T=8192, H=1024, E=8, D=2048. Router -> deterministic per-expert token lists
// -> per-expert gathered GEMM1(+silu) and GEMM2(+weighted scatter to out).

#define T_TOKENS 8192
#define HID 1024
#define NEXP 8
#define ED 2048
#define ED2 4096
#define CAP 8192  // per-expert list capacity

typedef __attribute__((ext_vector_type(8))) short bf16x8;
typedef __attribute__((ext_vector_type(4))) float f32x4;

__device__ __forceinline__ void gload_lds16(const void* g, void* lds) {
  __builtin_amdgcn_global_load_lds(
      (const __attribute__((address_space(1))) void*)g,
      (__attribute__((address_space(3))) void*)lds, 16, 0, 0);
}

// ---------------- f32 -> bf16 conversion ----------------
__global__ void cvt_kernel(const float* __restrict__ in, __hip_bfloat16* __restrict__ out, int n4) {
  int idx = blockIdx.x * blockDim.x + threadIdx.x;
  int stride = gridDim.x * blockDim.x;
  for (int i = idx; i < n4; i += stride) {
    float4 v = reinterpret_cast<const float4*>(in)[i];
    __hip_bfloat16 h0 = __float2bfloat16(v.x);
    __hip_bfloat16 h1 = __float2bfloat16(v.y);
    __hip_bfloat16 h2 = __float2bfloat16(v.z);
    __hip_bfloat16 h3 = __float2bfloat16(v.w);
    ushort4 o;
    o.x = *reinterpret_cast<unsigned short*>(&h0);
    o.y = *reinterpret_cast<unsigned short*>(&h1);
    o.z = *reinterpret_cast<unsigned short*>(&h2);
    o.w = *reinterpret_cast<unsigned short*>(&h3);
    reinterpret_cast<ushort4*>(out)[i] = o;
  }
}

// ---------------- router: logits -> softmax -> top2 -> renorm ----------------
__global__ __launch_bounds__(64) void router_kernel(const float* __restrict__ x,
                                                    const float* __restrict__ rw,
                                                    int2* __restrict__ top2i,
                                                    float2* __restrict__ top2w) {
  const int t = blockIdx.x;
  const int lane = threadIdx.x;
  const float* xr = x + (size_t)t * HID;
  float xv[16];
#pragma unroll
  for (int i = 0; i < 16; i++) xv[i] = xr[lane + 64 * i];
  float logit[NEXP];
#pragma unroll
  for (int e = 0; e < NEXP; e++) {
    const float* r = rw + e * HID;
    float p = 0.f;
#pragma unroll
    for (int i = 0; i < 16; i++) p += xv[i] * r[lane + 64 * i];
#pragma unroll
    for (int off = 32; off > 0; off >>= 1) p += __shfl_down(p, off);
    logit[e] = __shfl(p, 0);
  }
  if (lane == 0) {
    // top-2 (ties -> lowest index, matches jax.lax.top_k on softmax probs)
    int i0 = 0;
    for (int e = 1; e < NEXP; e++) if (logit[e] > logit[i0]) i0 = e;
    int i1 = (i0 == 0) ? 1 : 0;
    for (int e = 0; e < NEXP; e++) if (e != i0 && logit[e] > logit[i1]) i1 = e;
    float m = fmaxf(logit[i0], logit[i1]);
    float p0 = expf(logit[i0] - m), p1 = expf(logit[i1] - m);
    float s = p0 + p1;
    top2i[t] = make_int2(i0, i1);
    top2w[t] = make_float2(p0 / s, p1 / s);
  }
}

// ---------------- deterministic list build: ballot prefix scan ----------------
// 8 waves, wave w owns expert w. No atomics -> bit-deterministic slots.
__global__ __launch_bounds__(512) void build_lists(const int2* __restrict__ top2i,
                                                   const float2* __restrict__ top2w,
                                                   int* __restrict__ list,
                                                   float* __restrict__ wl,
                                                   int* __restrict__ count) {
  const int e = threadIdx.x >> 6;
  const int lane = threadIdx.x & 63;
  int* le = list + e * CAP;
  float* we = wl + e * CAP;
  int base = 0;
  for (int c = 0; c < T_TOKENS / 64; c++) {
    const int t = c * 64 + lane;
    int2 ti = top2i[t];
    float2 tw = top2w[t];
    bool a0 = (ti.x == e), a1 = (ti.y == e);
    bool assigned = a0 || a1;
    unsigned long long bal = __ballot(assigned);
    int prefix = __popcll(bal & ((1ull << lane) - 1ull));
    if (assigned) {
      le[base + prefix] = t;
      we[base + prefix] = a0 ? tw.x : tw.y;
    }
    base += __popcll(bal);
  }
  // pad to multiple of 128 with token 0 / weight 0 (reads safe, writes masked by count)
  int padded = (base + 127) & ~127;
  for (int p = base + lane; p < padded; p += 64) {
    le[p] = 0;
    we[p] = 0.f;
  }
  if (lane == 0) count[e] = base;
}

// ---------------- GEMM1: y1[r] = silu(x[list[r]] @ Wg^T) * (x[list[r]] @ Wu^T) ----------------
// block tile: 128 gathered rows x 64 gate-cols (+paired up-cols). 4 waves 2x2.
__global__ __launch_bounds__(256) void gemm1_silu(const __hip_bfloat16* __restrict__ A,
                                                  const __hip_bfloat16* __restrict__ B,
                                                  __hip_bfloat16* __restrict__ Y,
                                                  const int* __restrict__ list_e,
                                                  const int* __restrict__ cntp) {
  const int cnt = *cntp;
  const int m0 = blockIdx.x * 128;
  if (m0 >= cnt) return;
  __shared__ __hip_bfloat16 sA[128 * 64];
  __shared__ __hip_bfloat16 sBg[64 * 64];
  __shared__ __hip_bfloat16 sBu[64 * 64];
  const int tid = threadIdx.x;
  const int w = tid >> 6, lane = tid & 63;
  const int n0 = blockIdx.y * 64;
  const int wm = w >> 1, wn = w & 1;
  const int lr = lane >> 3;
  const int lc = (lane & 7) * 8;

  // gather token ids for this thread's 4 A-staging chunks
  int tok[4];
#pragma unroll
  for (int i = 0; i < 4; i++) tok[i] = list_e[m0 + (w * 4 + i) * 8 + lr];

  f32x4 accg[4][2] = {};
  f32x4 accu[4][2] = {};

  for (int k0 = 0; k0 < HID; k0 += 64) {
#pragma unroll
    for (int i = 0; i < 4; i++) {
      const int c = w * 4 + i;
      gload_lds16(A + (size_t)tok[i] * HID + k0 + lc, (char*)sA + c * 1024);
    }
#pragma unroll
    for (int i = 0; i < 2; i++) {
      const int c = w * 2 + i;
      gload_lds16(B + (size_t)(n0 + c * 8 + lr) * HID + k0 + lc, (char*)sBg + c * 1024);
      gload_lds16(B + (size_t)(ED + n0 + c * 8 + lr) * HID + k0 + lc, (char*)sBu + c * 1024);
    }
    __syncthreads();
#pragma unroll
    for (int ks = 0; ks < 2; ks++) {
      const int kc = ks * 32 + (lane >> 4) * 8;
      bf16x8 af[4], bg[2], bu[2];
#pragma unroll
      for (int m = 0; m < 4; m++)
        af[m] = *reinterpret_cast<const bf16x8*>(&sA[(wm * 64 + m * 16 + (lane & 15)) * 64 + kc]);
#pragma unroll
      for (int n = 0; n < 2; n++) {
        bg[n] = *reinterpret_cast<const bf16x8*>(&sBg[(wn * 32 + n * 16 + (lane & 15)) * 64 + kc]);
        bu[n] = *reinterpret_cast<const bf16x8*>(&sBu[(wn * 32 + n * 16 + (lane & 15)) * 64 + kc]);
      }
#pragma unroll
      for (int m = 0; m < 4; m++)
#pragma unroll
        for (int n = 0; n < 2; n++) {
          accg[m][n] = __builtin_amdgcn_mfma_f32_16x16x32_bf16(af[m], bg[n], accg[m][n], 0, 0, 0);
          accu[m][n] = __builtin_amdgcn_mfma_f32_16x16x32_bf16(af[m], bu[n], accu[m][n], 0, 0, 0);
        }
    }
    __syncthreads();
  }
#pragma unroll
  for (int m = 0; m < 4; m++)
#pragma unroll
    for (int n = 0; n < 2; n++) {
      const int row = m0 + wm * 64 + m * 16 + (lane >> 4) * 4;
      const int col = n0 + wn * 32 + n * 16 + (lane & 15);
#pragma unroll
      for (int r = 0; r < 4; r++) {
        float g = accg[m][n][r];
        float u = accu[m][n][r];
        float s = g / (1.f + expf(-g));
        Y[(size_t)(row + r) * ED + col] = __float2bfloat16(s * u);
      }
    }
}

// ---------------- GEMM2: out[list[r]] += wl[r] * (y1[r] @ down^T) ----------------
// block tile: 128 gathered rows x 64 cols. 4 waves 2x2 -> 64x32 each.
__global__ __launch_bounds__(256) void gemm2_acc(const __hip_bfloat16* __restrict__ A,
                                                 const __hip_bfloat16* __restrict__ B,
                                                 const int* __restrict__ list_e,
                                                 const float* __restrict__ wl_e,
                                                 const int* __restrict__ cntp,
                                                 float* __restrict__ out) {
  const int cnt = *cntp;
  const int m0 = blockIdx.x * 128;
  if (m0 >= cnt) return;
  __shared__ __hip_bfloat16 sA[128 * 64];
  __shared__ __hip_bfloat16 sB[64 * 64];
  const int tid = threadIdx.x;
  const int w = tid >> 6, lane = tid & 63;
  const int n0 = blockIdx.y * 64;
  const int wm = w >> 1, wn = w & 1;
  const int lr = lane >> 3;
  const int lc = (lane & 7) * 8;

  f32x4 acc[4][2] = {};

  for (int k0 = 0; k0 < ED; k0 += 64) {
#pragma unroll
    for (int i = 0; i < 4; i++) {
      const int c = w * 4 + i;
      gload_lds16(A + (size_t)(m0 + c * 8 + lr) * ED + k0 + lc, (char*)sA + c * 1024);
    }
#pragma unroll
    for (int i = 0; i < 2; i++) {
      const int c = w * 2 + i;
      gload_lds16(B + (size_t)(n0 + c * 8 + lr) * ED + k0 + lc, (char*)sB + c * 1024);
    }
    __syncthreads();
#pragma unroll
    for (int ks = 0; ks < 2; ks++) {
      const int kc = ks * 32 + (lane >> 4) * 8;
      bf16x8 af[4], bfr[2];
#pragma unroll
      for (int m = 0; m < 4; m++)
        af[m] = *reinterpret_cast<const bf16x8*>(&sA[(wm * 64 + m * 16 + (lane & 15)) * 64 + kc]);
#pragma unroll
      for (int n = 0; n < 2; n++)
        bfr[n] = *reinterpret_cast<const bf16x8*>(&sB[(wn * 32 + n * 16 + (lane & 15)) * 64 + kc]);
#pragma unroll
      for (int m = 0; m < 4; m++)
#pragma unroll
        for (int n = 0; n < 2; n++)
          acc[m][n] = __builtin_amdgcn_mfma_f32_16x16x32_bf16(af[m], bfr[n], acc[m][n], 0, 0, 0);
    }
    __syncthreads();
  }
#pragma unroll
  for (int m = 0; m < 4; m++) {
#pragma unroll
    for (int r = 0; r < 4; r++) {
      const int grow = m0 + wm * 64 + m * 16 + (lane >> 4) * 4 + r;
      if (grow < cnt) {
        const int t = list_e[grow];
        const float wgt = wl_e[grow];
#pragma unroll
        for (int n = 0; n < 2; n++) {
          const int col = n0 + wn * 32 + n * 16 + (lane & 15);
          out[(size_t)t * HID + col] += wgt * acc[m][n][r];
        }
      }
    }
  }
}

extern "C" void kernel_launch(void* const* d_in, const int* in_sizes, int n_in,
                              void* d_out, int out_size, void* d_ws, size_t ws_size,
                              hipStream_t stream) {
  const float* x = (const float*)d_in[0];
  const float* rw = (const float*)d_in[1];
  const float* up = (const float*)d_in[2];
  const float* down = (const float*)d_in[3];
  float* out = (float*)d_out;

  char* ws = (char*)d_ws;
  __hip_bfloat16* xb = (__hip_bfloat16*)(ws);                 // 16 MB
  __hip_bfloat16* upb = (__hip_bfloat16*)(ws + 16777216);     // 64 MB
  __hip_bfloat16* downb = (__hip_bfloat16*)(ws + 83886080);   // 32 MB
  __hip_bfloat16* y1 = (__hip_bfloat16*)(ws + 117440512);     // 32 MB
  char* misc = ws + 150994944;
  int2* top2i = (int2*)(misc);                  // 64 KB
  float2* top2w = (float2*)(misc + 65536);      // 64 KB
  int* list = (int*)(misc + 131072);            // 256 KB
  float* wl = (float*)(misc + 393216);          // 256 KB
  int* count = (int*)(misc + 655360);           // 32 B

  hipMemsetAsync(d_out, 0, (size_t)out_size * sizeof(float), stream);

  cvt_kernel<<<2048, 256, 0, stream>>>(x, xb, (T_TOKENS * HID) / 4);
  cvt_kernel<<<2048, 256, 0, stream>>>(up, upb, (NEXP * ED2 * HID) / 4);
  cvt_kernel<<<2048, 256, 0, stream>>>(down, downb, (NEXP * HID * ED) / 4);
  router_kernel<<<T_TOKENS, 64, 0, stream>>>(x, rw, top2i, top2w);
  build_lists<<<1, 512, 0, stream>>>(top2i, top2w, list, wl, count);

  dim3 g1(T_TOKENS / 128, ED / 64);   // 64 x 32, most blocks early-exit
  dim3 g2(T_TOKENS / 128, HID / 64);  // 64 x 16
  for (int e = 0; e < NEXP; e++) {
    gemm1_silu<<<g1, 256, 0, stream>>>(xb, upb + (size_t)e * ED2 * HID, y1,
                                       list + e * CAP, count + e);
    gemm2_acc<<<g2, 256, 0, stream>>>(y1, downb + (size_t)e * HID * ED,
                                      list + e * CAP, wl + e * CAP, count + e, out);
  }
}

// Round 3
// 526.490 us; speedup vs baseline: 2.6406x; 2.2008x over previous
//
#include <hip/hip_runtime.h>
#include <hip/hip_bf16.h>

// MoE FFN, grouped sparse dispatch (top-2 of 8), single GEMM launch per stage.
// Packed layout: expert e's tokens occupy rows [ebase[e], ebase[e]+cnt[e]) of a
// global list, padded to 128-row tiles. tile_e[] maps row-tile -> expert.
// GEMM2 writes unweighted partials; combine() does the deterministic weighted sum.

#define T_TOKENS 8192
#define HID 1024
#define NEXP 8
#define ED 2048
#define ED2 4096
#define MAXROWS 17408  // 2*T + 8*127 padding, rounded up
#define MAXTILES 136   // MAXROWS/128

typedef __attribute__((ext_vector_type(8))) short bf16x8;
typedef __attribute__((ext_vector_type(4))) float f32x4;

__device__ __forceinline__ void gload_lds16(const void* g, void* lds) {
  __builtin_amdgcn_global_load_lds(
      (const __attribute__((address_space(1))) void*)g,
      (__attribute__((address_space(3))) void*)lds, 16, 0, 0);
}

// ---------------- f32 -> bf16 conversion ----------------
__global__ void cvt_kernel(const float* __restrict__ in, __hip_bfloat16* __restrict__ out, int n4) {
  int idx = blockIdx.x * blockDim.x + threadIdx.x;
  int stride = gridDim.x * blockDim.x;
  for (int i = idx; i < n4; i += stride) {
    float4 v = reinterpret_cast<const float4*>(in)[i];
    __hip_bfloat16 h0 = __float2bfloat16(v.x);
    __hip_bfloat16 h1 = __float2bfloat16(v.y);
    __hip_bfloat16 h2 = __float2bfloat16(v.z);
    __hip_bfloat16 h3 = __float2bfloat16(v.w);
    ushort4 o;
    o.x = *reinterpret_cast<unsigned short*>(&h0);
    o.y = *reinterpret_cast<unsigned short*>(&h1);
    o.z = *reinterpret_cast<unsigned short*>(&h2);
    o.w = *reinterpret_cast<unsigned short*>(&h3);
    reinterpret_cast<ushort4*>(out)[i] = o;
  }
}

// ---------------- router ----------------
__global__ __launch_bounds__(64) void router_kernel(const float* __restrict__ x,
                                                    const float* __restrict__ rw,
                                                    int2* __restrict__ top2i,
                                                    float2* __restrict__ top2w) {
  const int t = blockIdx.x;
  const int lane = threadIdx.x;
  const float* xr = x + (size_t)t * HID;
  float xv[16];
#pragma unroll
  for (int i = 0; i < 16; i++) xv[i] = xr[lane + 64 * i];
  float logit[NEXP];
#pragma unroll
  for (int e = 0; e < NEXP; e++) {
    const float* r = rw + e * HID;
    float p = 0.f;
#pragma unroll
    for (int i = 0; i < 16; i++) p += xv[i] * r[lane + 64 * i];
#pragma unroll
    for (int off = 32; off > 0; off >>= 1) p += __shfl_down(p, off);
    logit[e] = __shfl(p, 0);
  }
  if (lane == 0) {
    int i0 = 0;
    for (int e = 1; e < NEXP; e++) if (logit[e] > logit[i0]) i0 = e;
    int i1 = (i0 == 0) ? 1 : 0;
    for (int e = 0; e < NEXP; e++) if (e != i0 && logit[e] > logit[i1]) i1 = e;
    float m = fmaxf(logit[i0], logit[i1]);
    float p0 = expf(logit[i0] - m), p1 = expf(logit[i1] - m);
    float s = p0 + p1;
    top2i[t] = make_int2(i0, i1);
    top2w[t] = make_float2(p0 / s, p1 / s);
  }
}

// ---------------- list build: two-pass deterministic ballot scan ----------------
// 8 waves, wave e owns expert e. Pass 1 counts, prefix -> ebase, pass 2 writes
// global packed list + per-token packed positions + tile->expert table.
__global__ __launch_bounds__(512) void build_lists(const int2* __restrict__ top2i,
                                                   int* __restrict__ list,
                                                   int2* __restrict__ posArr,
                                                   int* __restrict__ tile_e,
                                                   int* __restrict__ meta) {
  __shared__ int s_cnt[NEXP];
  __shared__ int s_base[NEXP + 1];
  const int e = threadIdx.x >> 6;
  const int lane = threadIdx.x & 63;

  // pass 1: count
  int cnt = 0;
  for (int c = 0; c < T_TOKENS / 64; c++) {
    const int t = c * 64 + lane;
    int2 ti = top2i[t];
    bool assigned = (ti.x == e) || (ti.y == e);
    cnt += __popcll(__ballot(assigned));
  }
  if (lane == 0) s_cnt[e] = cnt;
  __syncthreads();
  if (threadIdx.x == 0) {
    int acc = 0;
    for (int i = 0; i < NEXP; i++) {
      s_base[i] = acc;
      acc += (s_cnt[i] + 127) & ~127;
    }
    s_base[NEXP] = acc;
    meta[0] = acc / 128;  // total tiles
  }
  __syncthreads();
  const int ebase = s_base[e];
  const int padded = ((s_cnt[e] + 127) & ~127);

  // pass 2: write list + positions
  int base = 0;
  for (int c = 0; c < T_TOKENS / 64; c++) {
    const int t = c * 64 + lane;
    int2 ti = top2i[t];
    bool a0 = (ti.x == e);
    bool assigned = a0 || (ti.y == e);
    unsigned long long bal = __ballot(assigned);
    int prefix = __popcll(bal & ((1ull << lane) - 1ull));
    if (assigned) {
      int g = ebase + base + prefix;
      list[g] = t;
      if (a0) posArr[t].x = g; else posArr[t].y = g;
    }
    base += __popcll(bal);
  }
  // pad with token 0 (computed but never combined)
  for (int p = base + lane; p < padded; p += 64) list[ebase + p] = 0;
  // tile table
  for (int i = lane; i < padded / 128; i += 64) tile_e[ebase / 128 + i] = e;
}

// ---------------- GEMM1 (grouped): y1[g] = silu(x[list[g]]@Wg^T)*(x[list[g]]@Wu^T) ----------------
__global__ __launch_bounds__(256) void gemm1_silu(const __hip_bfloat16* __restrict__ A,
                                                  const __hip_bfloat16* __restrict__ Ball,
                                                  __hip_bfloat16* __restrict__ Y,
                                                  const int* __restrict__ list,
                                                  const int* __restrict__ tile_e,
                                                  const int* __restrict__ meta) {
  const int bx = blockIdx.x;
  if (bx >= meta[0]) return;
  const __hip_bfloat16* B = Ball + (size_t)tile_e[bx] * ED2 * HID;
  const int rowbase = bx * 128;
  __shared__ __hip_bfloat16 sA[128 * 64];
  __shared__ __hip_bfloat16 sBg[64 * 64];
  __shared__ __hip_bfloat16 sBu[64 * 64];
  const int tid = threadIdx.x;
  const int w = tid >> 6, lane = tid & 63;
  const int n0 = blockIdx.y * 64;
  const int wm = w >> 1, wn = w & 1;
  const int lr = lane >> 3;
  const int lc = (lane & 7) * 8;

  int tok[4];
#pragma unroll
  for (int i = 0; i < 4; i++) tok[i] = list[rowbase + (w * 4 + i) * 8 + lr];

  f32x4 accg[4][2] = {};
  f32x4 accu[4][2] = {};

  for (int k0 = 0; k0 < HID; k0 += 64) {
#pragma unroll
    for (int i = 0; i < 4; i++) {
      const int c = w * 4 + i;
      gload_lds16(A + (size_t)tok[i] * HID + k0 + lc, (char*)sA + c * 1024);
    }
#pragma unroll
    for (int i = 0; i < 2; i++) {
      const int c = w * 2 + i;
      gload_lds16(B + (size_t)(n0 + c * 8 + lr) * HID + k0 + lc, (char*)sBg + c * 1024);
      gload_lds16(B + (size_t)(ED + n0 + c * 8 + lr) * HID + k0 + lc, (char*)sBu + c * 1024);
    }
    __syncthreads();
#pragma unroll
    for (int ks = 0; ks < 2; ks++) {
      const int kc = ks * 32 + (lane >> 4) * 8;
      bf16x8 af[4], bg[2], bu[2];
#pragma unroll
      for (int m = 0; m < 4; m++)
        af[m] = *reinterpret_cast<const bf16x8*>(&sA[(wm * 64 + m * 16 + (lane & 15)) * 64 + kc]);
#pragma unroll
      for (int n = 0; n < 2; n++) {
        bg[n] = *reinterpret_cast<const bf16x8*>(&sBg[(wn * 32 + n * 16 + (lane & 15)) * 64 + kc]);
        bu[n] = *reinterpret_cast<const bf16x8*>(&sBu[(wn * 32 + n * 16 + (lane & 15)) * 64 + kc]);
      }
#pragma unroll
      for (int m = 0; m < 4; m++)
#pragma unroll
        for (int n = 0; n < 2; n++) {
          accg[m][n] = __builtin_amdgcn_mfma_f32_16x16x32_bf16(af[m], bg[n], accg[m][n], 0, 0, 0);
          accu[m][n] = __builtin_amdgcn_mfma_f32_16x16x32_bf16(af[m], bu[n], accu[m][n], 0, 0, 0);
        }
    }
    __syncthreads();
  }
#pragma unroll
  for (int m = 0; m < 4; m++)
#pragma unroll
    for (int n = 0; n < 2; n++) {
      const int row = rowbase + wm * 64 + m * 16 + (lane >> 4) * 4;
      const int col = n0 + wn * 32 + n * 16 + (lane & 15);
#pragma unroll
      for (int r = 0; r < 4; r++) {
        float g = accg[m][n][r];
        float u = accu[m][n][r];
        float s = g / (1.f + expf(-g));
        Y[(size_t)(row + r) * ED + col] = __float2bfloat16(s * u);
      }
    }
}

// ---------------- GEMM2 (grouped): part[g] = y1[g] @ down_e^T (unweighted) ----------------
__global__ __launch_bounds__(256) void gemm2_part(const __hip_bfloat16* __restrict__ A,
                                                  const __hip_bfloat16* __restrict__ Ball,
                                                  float* __restrict__ part,
                                                  const int* __restrict__ tile_e,
                                                  const int* __restrict__ meta) {
  const int bx = blockIdx.x;
  if (bx >= meta[0]) return;
  const __hip_bfloat16* B = Ball + (size_t)tile_e[bx] * HID * ED;
  const int rowbase = bx * 128;
  __shared__ __hip_bfloat16 sA[128 * 64];
  __shared__ __hip_bfloat16 sB[64 * 64];
  const int tid = threadIdx.x;
  const int w = tid >> 6, lane = tid & 63;
  const int n0 = blockIdx.y * 64;
  const int wm = w >> 1, wn = w & 1;
  const int lr = lane >> 3;
  const int lc = (lane & 7) * 8;

  f32x4 acc[4][2] = {};

  for (int k0 = 0; k0 < ED; k0 += 64) {
#pragma unroll
    for (int i = 0; i < 4; i++) {
      const int c = w * 4 + i;
      gload_lds16(A + (size_t)(rowbase + c * 8 + lr) * ED + k0 + lc, (char*)sA + c * 1024);
    }
#pragma unroll
    for (int i = 0; i < 2; i++) {
      const int c = w * 2 + i;
      gload_lds16(B + (size_t)(n0 + c * 8 + lr) * ED + k0 + lc, (char*)sB + c * 1024);
    }
    __syncthreads();
#pragma unroll
    for (int ks = 0; ks < 2; ks++) {
      const int kc = ks * 32 + (lane >> 4) * 8;
      bf16x8 af[4], bfr[2];
#pragma unroll
      for (int m = 0; m < 4; m++)
        af[m] = *reinterpret_cast<const bf16x8*>(&sA[(wm * 64 + m * 16 + (lane & 15)) * 64 + kc]);
#pragma unroll
      for (int n = 0; n < 2; n++)
        bfr[n] = *reinterpret_cast<const bf16x8*>(&sB[(wn * 32 + n * 16 + (lane & 15)) * 64 + kc]);
#pragma unroll
      for (int m = 0; m < 4; m++)
#pragma unroll
        for (int n = 0; n < 2; n++)
          acc[m][n] = __builtin_amdgcn_mfma_f32_16x16x32_bf16(af[m], bfr[n], acc[m][n], 0, 0, 0);
    }
    __syncthreads();
  }
#pragma unroll
  for (int m = 0; m < 4; m++)
#pragma unroll
    for (int n = 0; n < 2; n++) {
      const int row = rowbase + wm * 64 + m * 16 + (lane >> 4) * 4;
      const int col = n0 + wn * 32 + n * 16 + (lane & 15);
#pragma unroll
      for (int r = 0; r < 4; r++)
        part[(size_t)(row + r) * HID + col] = acc[m][n][r];
    }
}

// ---------------- combine: out[t] = w0*part[pos0] + w1*part[pos1] ----------------
__global__ void combine_kernel(const float* __restrict__ part,
                               const int2* __restrict__ posArr,
                               const float2* __restrict__ top2w,
                               float* __restrict__ out) {
  const int total = T_TOKENS * (HID / 4);
  int idx = blockIdx.x * blockDim.x + threadIdx.x;
  int stride = gridDim.x * blockDim.x;
  for (int i = idx; i < total; i += stride) {
    const int t = i >> 8;          // HID/4 = 256 float4 per row
    const int c = i & 255;
    int2 p = posArr[t];
    float2 w = top2w[t];
    float4 a = reinterpret_cast<const float4*>(part)[(size_t)p.x * 256 + c];
    float4 b = reinterpret_cast<const float4*>(part)[(size_t)p.y * 256 + c];
    float4 o;
    o.x = w.x * a.x + w.y * b.x;
    o.y = w.x * a.y + w.y * b.y;
    o.z = w.x * a.z + w.y * b.z;
    o.w = w.x * a.w + w.y * b.w;
    reinterpret_cast<float4*>(out)[i] = o;
  }
}

extern "C" void kernel_launch(void* const* d_in, const int* in_sizes, int n_in,
                              void* d_out, int out_size, void* d_ws, size_t ws_size,
                              hipStream_t stream) {
  const float* x = (const float*)d_in[0];
  const float* rw = (const float*)d_in[1];
  const float* up = (const float*)d_in[2];
  const float* down = (const float*)d_in[3];
  float* out = (float*)d_out;

  char* ws = (char*)d_ws;
  __hip_bfloat16* xb = (__hip_bfloat16*)(ws);                  // 16 MB
  __hip_bfloat16* upb = (__hip_bfloat16*)(ws + 16777216);      // 64 MB
  __hip_bfloat16* downb = (__hip_bfloat16*)(ws + 83886080);    // 32 MB
  __hip_bfloat16* y1 = (__hip_bfloat16*)(ws + 117440512);      // 71.3 MB (MAXROWS x ED bf16)
  float* part = (float*)(ws + 188743680);                      // 71.3 MB (MAXROWS x HID f32)
  char* misc = ws + 260046848;
  int2* top2i = (int2*)(misc);                   // 64 KB
  float2* top2w = (float2*)(misc + 65536);       // 64 KB
  int* list = (int*)(misc + 131072);             // 128 KB slot
  int2* posArr = (int2*)(misc + 262144);         // 64 KB
  int* tile_e = (int*)(misc + 327680);           // 4 KB slot
  int* meta = (int*)(misc + 331776);             // 4 KB slot

  cvt_kernel<<<2048, 256, 0, stream>>>(x, xb, (T_TOKENS * HID) / 4);
  cvt_kernel<<<2048, 256, 0, stream>>>(up, upb, (NEXP * ED2 * HID) / 4);
  cvt_kernel<<<2048, 256, 0, stream>>>(down, downb, (NEXP * HID * ED) / 4);
  router_kernel<<<T_TOKENS, 64, 0, stream>>>(x, rw, top2i, top2w);
  build_lists<<<1, 512, 0, stream>>>(top2i, list, posArr, tile_e, meta);

  dim3 g1(MAXTILES, ED / 64);   // 136 x 32
  dim3 g2(MAXTILES, HID / 64);  // 136 x 16
  gemm1_silu<<<g1, 256, 0, stream>>>(xb, upb, y1, list, tile_e, meta);
  gemm2_part<<<g2, 256, 0, stream>>>(y1, downb, part, tile_e, meta);
  combine_kernel<<<2048, 256, 0, stream>>>(part, posArr, top2w, out);
}

// Round 4
// 438.516 us; speedup vs baseline: 3.1704x; 1.2006x over previous
//
#include <hip/hip_runtime.h>
#include <hip/hip_bf16.h>

// MoE FFN, grouped sparse dispatch (top-2 of 8), deep-pipelined GEMMs.
// T-stack: T1 XCD swizzle, T2 LDS XOR-swizzle (both-sides with global_load_lds),
// T3/T4 double-buffer + counted vmcnt + raw barriers, T5 setprio around MFMA.

#define T_TOKENS 8192
#define HID 1024
#define NEXP 8
#define ED 2048
#define ED2 4096
#define MAXROWS 18432   // sum of per-expert counts padded to 256
#define MAXT256 72      // MAXROWS/256
#define MAXT128 144

typedef __hip_bfloat16 bf16;
typedef __attribute__((ext_vector_type(8))) short bf16x8;
typedef __attribute__((ext_vector_type(4))) float f32x4;

#define WAITVM(N) asm volatile("s_waitcnt vmcnt(" #N ")" ::: "memory")
#define BAR() asm volatile("s_barrier" ::: "memory")

__device__ __forceinline__ void gload_lds16(const void* g, void* lds) {
  __builtin_amdgcn_global_load_lds(
      (const __attribute__((address_space(1))) void*)g,
      (__attribute__((address_space(3))) void*)lds, 16, 0, 0);
}

__device__ __forceinline__ bf16x8 lds_read_swz(const bf16* base, int row, int kb) {
  // logical (row, k-byte kb in [0,128)) -> physical with T2 swizzle
  int off = row * 128 + (kb ^ ((row & 7) << 4));
  return *reinterpret_cast<const bf16x8*>(reinterpret_cast<const char*>(base) + off);
}

// ---------------- f32 -> bf16 conversion (weights) ----------------
__global__ void cvt_kernel(const float* __restrict__ in, bf16* __restrict__ out, int n4) {
  int idx = blockIdx.x * blockDim.x + threadIdx.x;
  int stride = gridDim.x * blockDim.x;
  for (int i = idx; i < n4; i += stride) {
    float4 v = reinterpret_cast<const float4*>(in)[i];
    bf16 h0 = __float2bfloat16(v.x), h1 = __float2bfloat16(v.y);
    bf16 h2 = __float2bfloat16(v.z), h3 = __float2bfloat16(v.w);
    ushort4 o;
    o.x = *reinterpret_cast<unsigned short*>(&h0);
    o.y = *reinterpret_cast<unsigned short*>(&h1);
    o.z = *reinterpret_cast<unsigned short*>(&h2);
    o.w = *reinterpret_cast<unsigned short*>(&h3);
    reinterpret_cast<ushort4*>(out)[i] = o;
  }
}

// ---------------- router (+ x -> bf16) ----------------
__global__ __launch_bounds__(64) void router_kernel(const float* __restrict__ x,
                                                    const float* __restrict__ rw,
                                                    bf16* __restrict__ xb,
                                                    int2* __restrict__ top2i,
                                                    float2* __restrict__ top2w) {
  const int t = blockIdx.x;
  const int lane = threadIdx.x;
  const float* xr = x + (size_t)t * HID;
  float xv[16];
#pragma unroll
  for (int i = 0; i < 16; i++) xv[i] = xr[lane + 64 * i];
#pragma unroll
  for (int i = 0; i < 16; i++) xb[(size_t)t * HID + lane + 64 * i] = __float2bfloat16(xv[i]);
  float logit[NEXP];
#pragma unroll
  for (int e = 0; e < NEXP; e++) {
    const float* r = rw + e * HID;
    float p = 0.f;
#pragma unroll
    for (int i = 0; i < 16; i++) p += xv[i] * r[lane + 64 * i];
#pragma unroll
    for (int off = 32; off > 0; off >>= 1) p += __shfl_down(p, off);
    logit[e] = __shfl(p, 0);
  }
  if (lane == 0) {
    int i0 = 0;
    for (int e = 1; e < NEXP; e++) if (logit[e] > logit[i0]) i0 = e;
    int i1 = (i0 == 0) ? 1 : 0;
    for (int e = 0; e < NEXP; e++) if (e != i0 && logit[e] > logit[i1]) i1 = e;
    float m = fmaxf(logit[i0], logit[i1]);
    float p0 = expf(logit[i0] - m), p1 = expf(logit[i1] - m);
    float s = p0 + p1;
    top2i[t] = make_int2(i0, i1);
    top2w[t] = make_float2(p0 / s, p1 / s);
  }
}

// ---------------- list build (pad to 256) ----------------
__global__ __launch_bounds__(512) void build_lists(const int2* __restrict__ top2i,
                                                   int* __restrict__ list,
                                                   int2* __restrict__ posArr,
                                                   int* __restrict__ tile_e,
                                                   int* __restrict__ meta) {
  __shared__ int s_cnt[NEXP];
  __shared__ int s_base[NEXP + 1];
  const int e = threadIdx.x >> 6;
  const int lane = threadIdx.x & 63;

  int cnt = 0;
  for (int c = 0; c < T_TOKENS / 64; c++) {
    const int t = c * 64 + lane;
    int2 ti = top2i[t];
    cnt += __popcll(__ballot((ti.x == e) || (ti.y == e)));
  }
  if (lane == 0) s_cnt[e] = cnt;
  __syncthreads();
  if (threadIdx.x == 0) {
    int acc = 0;
    for (int i = 0; i < NEXP; i++) {
      s_base[i] = acc;
      acc += (s_cnt[i] + 255) & ~255;
    }
    s_base[NEXP] = acc;
    meta[0] = acc / 256;  // total 256-row tiles
  }
  __syncthreads();
  const int ebase = s_base[e];
  const int padded = (s_cnt[e] + 255) & ~255;

  int base = 0;
  for (int c = 0; c < T_TOKENS / 64; c++) {
    const int t = c * 64 + lane;
    int2 ti = top2i[t];
    bool a0 = (ti.x == e);
    bool assigned = a0 || (ti.y == e);
    unsigned long long bal = __ballot(assigned);
    int prefix = __popcll(bal & ((1ull << lane) - 1ull));
    if (assigned) {
      int g = ebase + base + prefix;
      list[g] = t;
      if (a0) posArr[t].x = g; else posArr[t].y = g;
    }
    base += __popcll(bal);
  }
  for (int p = base + lane; p < padded; p += 64) list[ebase + p] = 0;
  for (int i = lane; i < padded / 256; i += 64) tile_e[ebase / 256 + i] = e;
}

// ---------------- GEMM1: y1 = silu(x@Wg^T)*(x@Wu^T), grouped, 256x(128 dual) ----------------
// 8 waves 2M x 4N; per wave 128 rows x 32 D-cols, dual (gate+up) accumulators.
__global__ __launch_bounds__(512) void gemm1_silu(const bf16* __restrict__ A,
                                                  const bf16* __restrict__ Ball,
                                                  bf16* __restrict__ Y,
                                                  const int* __restrict__ list,
                                                  const int* __restrict__ tile_e,
                                                  const int* __restrict__ meta) {
  __shared__ bf16 sA[2][256 * 64];
  __shared__ bf16 sBg[2][128 * 64];
  __shared__ bf16 sBu[2][128 * 64];
  const int nwg = MAXT256 * 16;               // 1152, %8==0
  const int id2 = ((int)blockIdx.x % 8) * (nwg / 8) + (int)blockIdx.x / 8;  // T1
  const int dn = id2 % 16;
  const int tile = id2 / 16;
  if (tile >= meta[0]) return;
  const bf16* B = Ball + (size_t)tile_e[tile] * (ED2 * HID);
  const int rowbase = tile * 256;
  const int tid = threadIdx.x;
  const int w = tid >> 6, lane = tid & 63;
  const int wm = w >> 2, wn = w & 3;
  const int srcswz = 16 * ((lane & 7) ^ ((lane >> 3) & 7));
  const int dn0 = dn * 128;

  int tok[4];
#pragma unroll
  for (int i = 0; i < 4; i++) tok[i] = list[rowbase + w * 32 + i * 8 + (lane >> 3)];

  f32x4 accg[8][2] = {};
  f32x4 accu[8][2] = {};

  auto stage = [&](int kt, int buf) {
    const int kb0 = kt * 128;  // k-byte base
#pragma unroll
    for (int i = 0; i < 4; i++)
      gload_lds16((const char*)A + (size_t)tok[i] * (HID * 2) + kb0 + srcswz,
                  (char*)&sA[buf][0] + (w * 32 + i * 8) * 128);
#pragma unroll
    for (int i = 0; i < 2; i++) {
      const int c = w * 2 + i;
      const int grow = dn0 + c * 8 + (lane >> 3);
      gload_lds16((const char*)B + (size_t)grow * (HID * 2) + kb0 + srcswz,
                  (char*)&sBg[buf][0] + c * 1024);
      gload_lds16((const char*)B + (size_t)(ED + grow) * (HID * 2) + kb0 + srcswz,
                  (char*)&sBu[buf][0] + c * 1024);
    }
  };

  const int NT = HID / 64;  // 16
  stage(0, 0);
  for (int t = 0; t < NT; ++t) {
    const int cur = t & 1;
    if (t + 1 < NT) { stage(t + 1, cur ^ 1); WAITVM(8); }
    else { WAITVM(0); }
    BAR();
    const bf16* pA = &sA[cur][0];
    const bf16* pBg = &sBg[cur][0];
    const bf16* pBu = &sBu[cur][0];
    const int arow0 = wm * 128 + (lane & 15);
    const int brow0 = wn * 32 + (lane & 15);
    const int kb0 = (lane >> 4) * 16;
    bf16x8 a[4][2], bg[2][2], bu[2][2];
    // q0: A mh0 + Bg reads, gate MFMA (m 0..3)
#pragma unroll
    for (int m = 0; m < 4; m++)
#pragma unroll
      for (int ks = 0; ks < 2; ks++) a[m][ks] = lds_read_swz(pA, arow0 + m * 16, kb0 + ks * 64);
#pragma unroll
    for (int n = 0; n < 2; n++)
#pragma unroll
      for (int ks = 0; ks < 2; ks++) bg[n][ks] = lds_read_swz(pBg, brow0 + n * 16, kb0 + ks * 64);
    __builtin_amdgcn_s_setprio(1);
#pragma unroll
    for (int m = 0; m < 4; m++)
#pragma unroll
      for (int n = 0; n < 2; n++)
#pragma unroll
        for (int ks = 0; ks < 2; ks++)
          accg[m][n] = __builtin_amdgcn_mfma_f32_16x16x32_bf16(a[m][ks], bg[n][ks], accg[m][n], 0, 0, 0);
    __builtin_amdgcn_s_setprio(0);
    // q1: Bu reads, up MFMA (m 0..3)
#pragma unroll
    for (int n = 0; n < 2; n++)
#pragma unroll
      for (int ks = 0; ks < 2; ks++) bu[n][ks] = lds_read_swz(pBu, brow0 + n * 16, kb0 + ks * 64);
    __builtin_amdgcn_s_setprio(1);
#pragma unroll
    for (int m = 0; m < 4; m++)
#pragma unroll
      for (int n = 0; n < 2; n++)
#pragma unroll
        for (int ks = 0; ks < 2; ks++)
          accu[m][n] = __builtin_amdgcn_mfma_f32_16x16x32_bf16(a[m][ks], bu[n][ks], accu[m][n], 0, 0, 0);
    __builtin_amdgcn_s_setprio(0);
    // q2: A mh1 reads, gate MFMA (m 4..7)
#pragma unroll
    for (int m = 0; m < 4; m++)
#pragma unroll
      for (int ks = 0; ks < 2; ks++) a[m][ks] = lds_read_swz(pA, arow0 + 64 + m * 16, kb0 + ks * 64);
    __builtin_amdgcn_s_setprio(1);
#pragma unroll
    for (int m = 0; m < 4; m++)
#pragma unroll
      for (int n = 0; n < 2; n++)
#pragma unroll
        for (int ks = 0; ks < 2; ks++)
          accg[m + 4][n] = __builtin_amdgcn_mfma_f32_16x16x32_bf16(a[m][ks], bg[n][ks], accg[m + 4][n], 0, 0, 0);
    __builtin_amdgcn_s_setprio(0);
    // q3: up MFMA (m 4..7)
    __builtin_amdgcn_s_setprio(1);
#pragma unroll
    for (int m = 0; m < 4; m++)
#pragma unroll
      for (int n = 0; n < 2; n++)
#pragma unroll
        for (int ks = 0; ks < 2; ks++)
          accu[m + 4][n] = __builtin_amdgcn_mfma_f32_16x16x32_bf16(a[m][ks], bu[n][ks], accu[m + 4][n], 0, 0, 0);
    __builtin_amdgcn_s_setprio(0);
    BAR();
  }
  // epilogue: silu(g)*u -> bf16
#pragma unroll
  for (int m = 0; m < 8; m++)
#pragma unroll
    for (int n = 0; n < 2; n++) {
      const int row = rowbase + wm * 128 + m * 16 + (lane >> 4) * 4;
      const int col = dn0 + wn * 32 + n * 16 + (lane & 15);
#pragma unroll
      for (int r = 0; r < 4; r++) {
        float g = accg[m][n][r];
        float u = accu[m][n][r];
        float s = g * __builtin_amdgcn_rcpf(1.f + exp2f(g * -1.44269504f));
        Y[(size_t)(row + r) * ED + col] = __float2bfloat16(s * u);
      }
    }
}

// ---------------- GEMM2: part = y1 @ down_e^T (unweighted), 128x256 ----------------
// 8 waves 2M x 4N; per wave 64 rows x 64 cols.
__global__ __launch_bounds__(512) void gemm2_part(const bf16* __restrict__ A,
                                                  const bf16* __restrict__ Ball,
                                                  float* __restrict__ part,
                                                  const int* __restrict__ tile_e,
                                                  const int* __restrict__ meta) {
  __shared__ bf16 sA[2][128 * 64];
  __shared__ bf16 sB[2][256 * 64];
  const int nwg = MAXT128 * 4;                // 576, %8==0
  const int id2 = ((int)blockIdx.x % 8) * (nwg / 8) + (int)blockIdx.x / 8;  // T1
  const int bn = id2 % 4;
  const int tile = id2 / 4;                   // 128-row tile
  if (tile >= meta[0] * 2) return;
  const bf16* B = Ball + (size_t)tile_e[tile >> 1] * (HID * ED);
  const int rowbase = tile * 128;
  const int tid = threadIdx.x;
  const int w = tid >> 6, lane = tid & 63;
  const int wm = w >> 2, wn = w & 3;
  const int srcswz = 16 * ((lane & 7) ^ ((lane >> 3) & 7));
  const int bn0 = bn * 256;

  f32x4 acc[4][4] = {};

  auto stage = [&](int kt, int buf) {
    const int kb0 = kt * 128;
#pragma unroll
    for (int i = 0; i < 2; i++) {
      const int c = w * 2 + i;
      gload_lds16((const char*)A + (size_t)(rowbase + c * 8 + (lane >> 3)) * (ED * 2) + kb0 + srcswz,
                  (char*)&sA[buf][0] + c * 1024);
    }
#pragma unroll
    for (int i = 0; i < 4; i++) {
      const int c = w * 4 + i;
      gload_lds16((const char*)B + (size_t)(bn0 + c * 8 + (lane >> 3)) * (ED * 2) + kb0 + srcswz,
                  (char*)&sB[buf][0] + c * 1024);
    }
  };

  const int NT = ED / 64;  // 32
  stage(0, 0);
  for (int t = 0; t < NT; ++t) {
    const int cur = t & 1;
    if (t + 1 < NT) { stage(t + 1, cur ^ 1); WAITVM(6); }
    else { WAITVM(0); }
    BAR();
    const bf16* pA = &sA[cur][0];
    const bf16* pB = &sB[cur][0];
    const int arow0 = wm * 64 + (lane & 15);
    const int brow0 = wn * 64 + (lane & 15);
    const int kb0 = (lane >> 4) * 16;
    bf16x8 a[2][2], b[4][2];
    // phase 0: A mh0 + all B, MFMA m0..1
#pragma unroll
    for (int m = 0; m < 2; m++)
#pragma unroll
      for (int ks = 0; ks < 2; ks++) a[m][ks] = lds_read_swz(pA, arow0 + m * 16, kb0 + ks * 64);
#pragma unroll
    for (int n = 0; n < 4; n++)
#pragma unroll
      for (int ks = 0; ks < 2; ks++) b[n][ks] = lds_read_swz(pB, brow0 + n * 16, kb0 + ks * 64);
    __builtin_amdgcn_s_setprio(1);
#pragma unroll
    for (int m = 0; m < 2; m++)
#pragma unroll
      for (int n = 0; n < 4; n++)
#pragma unroll
        for (int ks = 0; ks < 2; ks++)
          acc[m][n] = __builtin_amdgcn_mfma_f32_16x16x32_bf16(a[m][ks], b[n][ks], acc[m][n], 0, 0, 0);
    __builtin_amdgcn_s_setprio(0);
    // phase 1: A mh1, MFMA m2..3
#pragma unroll
    for (int m = 0; m < 2; m++)
#pragma unroll
      for (int ks = 0; ks < 2; ks++) a[m][ks] = lds_read_swz(pA, arow0 + 32 + m * 16, kb0 + ks * 64);
    __builtin_amdgcn_s_setprio(1);
#pragma unroll
    for (int m = 0; m < 2; m++)
#pragma unroll
      for (int n = 0; n < 4; n++)
#pragma unroll
        for (int ks = 0; ks < 2; ks++)
          acc[m + 2][n] = __builtin_amdgcn_mfma_f32_16x16x32_bf16(a[m][ks], b[n][ks], acc[m + 2][n], 0, 0, 0);
    __builtin_amdgcn_s_setprio(0);
    BAR();
  }
#pragma unroll
  for (int m = 0; m < 4; m++)
#pragma unroll
    for (int n = 0; n < 4; n++) {
      const int row = rowbase + wm * 64 + m * 16 + (lane >> 4) * 4;
      const int col = bn0 + wn * 64 + n * 16 + (lane & 15);
#pragma unroll
      for (int r = 0; r < 4; r++)
        part[(size_t)(row + r) * HID + col] = acc[m][n][r];
    }
}

// ---------------- combine ----------------
__global__ void combine_kernel(const float* __restrict__ part,
                               const int2* __restrict__ posArr,
                               const float2* __restrict__ top2w,
                               float* __restrict__ out) {
  const int total = T_TOKENS * (HID / 4);
  int idx = blockIdx.x * blockDim.x + threadIdx.x;
  int stride = gridDim.x * blockDim.x;
  for (int i = idx; i < total; i += stride) {
    const int t = i >> 8;
    const int c = i & 255;
    int2 p = posArr[t];
    float2 w = top2w[t];
    float4 a = reinterpret_cast<const float4*>(part)[(size_t)p.x * 256 + c];
    float4 b = reinterpret_cast<const float4*>(part)[(size_t)p.y * 256 + c];
    float4 o;
    o.x = w.x * a.x + w.y * b.x;
    o.y = w.x * a.y + w.y * b.y;
    o.z = w.x * a.z + w.y * b.z;
    o.w = w.x * a.w + w.y * b.w;
    reinterpret_cast<float4*>(out)[i] = o;
  }
}

extern "C" void kernel_launch(void* const* d_in, const int* in_sizes, int n_in,
                              void* d_out, int out_size, void* d_ws, size_t ws_size,
                              hipStream_t stream) {
  const float* x = (const float*)d_in[0];
  const float* rw = (const float*)d_in[1];
  const float* up = (const float*)d_in[2];
  const float* down = (const float*)d_in[3];
  float* out = (float*)d_out;

  char* ws = (char*)d_ws;
  bf16* xb = (bf16*)(ws);                       // 16 MB
  bf16* upb = (bf16*)(ws + 16777216);           // 64 MB
  bf16* downb = (bf16*)(ws + 83886080);         // 32 MB
  bf16* y1 = (bf16*)(ws + 117440512);           // 72 MB (MAXROWS x ED bf16)
  float* part = (float*)(ws + 192937984);       // 72 MB (MAXROWS x HID f32)
  char* misc = ws + 268435456;
  int2* top2i = (int2*)(misc);                  // 64 KB
  float2* top2w = (float2*)(misc + 65536);      // 64 KB
  int* list = (int*)(misc + 131072);            // 128 KB slot
  int2* posArr = (int2*)(misc + 262144);        // 64 KB
  int* tile_e = (int*)(misc + 327680);          // 4 KB slot
  int* meta = (int*)(misc + 331776);            // 4 KB slot

  cvt_kernel<<<2048, 256, 0, stream>>>(up, upb, (NEXP * ED2 * HID) / 4);
  cvt_kernel<<<2048, 256, 0, stream>>>(down, downb, (NEXP * HID * ED) / 4);
  router_kernel<<<T_TOKENS, 64, 0, stream>>>(x, rw, xb, top2i, top2w);
  build_lists<<<1, 512, 0, stream>>>(top2i, list, posArr, tile_e, meta);

  gemm1_silu<<<MAXT256 * 16, 512, 0, stream>>>(xb, upb, y1, list, tile_e, meta);
  gemm2_part<<<MAXT128 * 4, 512, 0, stream>>>(y1, downb, part, tile_e, meta);
  combine_kernel<<<2048, 256, 0, stream>>>(part, posArr, top2w, out);
}